// Round 8
// baseline (604.286 us; speedup 1.0000x reference)
//
#include <hip/hip_runtime.h>
#include <math.h>

// Fused morphological opening: erode(10x10 flat, SAME) then dilate(10x10 flat,
// SAME), NHWC fp32 [16,512,512,8]. One kernel; eroded intermediate in LDS.
//
// R7 post-mortem: producer/consumer wave split concentrated ALL compute in 2
// waves (serial per-thread streams, VALUBusy 10%) and spilled (VGPR capped
// 128 < 100-reg held prefetch + compute; WRITE 131->157 MB). R8 keeps R7's
// z-pipelining but reverts to R4's FULL-WIDTH parallel phases:
//   every thread: [issue next-tile P1 taps -> regs] -> P2(k) -> P3(k) ->
//   P4(k) -> P5(k) -> [reduce prefetched taps, ds_write other buffer].
// Overlap is structural: tile k+1's global-load latency hides under tile k's
// ~5us compute. No wave specialization; R4 task maps (246/164/128 tasks).
// Spill control: prefetch runs {9,8,8,8,8} -> held taps 17-18 f4 = 68-72
// VGPR; amdgpu_waves_per_eu(2,2) pins allocator budget at 256 (1 block/CU of
// 8 waves anyway due to 132.5 KB LDS).
// Raw s_barrier + lgkmcnt(0) only (NEVER __syncthreads: it drains vmcnt(0)
// and would serialize the prefetch). vmcnt waits appear only at v[] first use
// (compiler-inserted, in the consume step).
// Geometry: TH=32 (16 exact bands), RA=41 eroded rows, 50 px staged, S_A=101.
// NZ=8 -> grid (16,16,2) = 512 blocks = exactly 2 sequential blocks/CU.
// Boundary semantics (lax.reduce_window SAME): erosion pads input +inf (P1
// taps masked on rim); dilation pads the *eroded* image -inf outside [0,512)
// (P3 abs-row / P4 abs-px masks, rim blocks only). Verified scheme (R4 ok).
// Tripwire: WRITE_SIZE must be exactly 131072 KB (no spill).

#define W_F4   1024              // 512 px * 2 f4 (8 ch)
#define IMG_F4 (512 * W_F4)
#define TH     32                // output rows per tile (512/32 = 16 bands)
#define TW     32                // output px per tile
#define RA     41                // eroded rows staged = TH + 9
#define CA     100               // staged cols (f4) = (TW + 18) * 2
#define S_A    101               // row stride (f4)
#define BUF_F4 (RA * S_A)        // 4141 f4 = 66,256 B per buffer
#define NZ     8                 // z-tiles per block

__device__ __forceinline__ float4 f4min(float4 a, float4 b) {
    return make_float4(fminf(a.x,b.x), fminf(a.y,b.y), fminf(a.z,b.z), fminf(a.w,b.w));
}
__device__ __forceinline__ float4 f4max(float4 a, float4 b) {
    return make_float4(fmaxf(a.x,b.x), fmaxf(a.y,b.y), fmaxf(a.z,b.z), fmaxf(a.w,b.w));
}
template<bool MIN>
__device__ __forceinline__ float4 f4op(float4 a, float4 b) {
    return MIN ? f4min(a, b) : f4max(a, b);
}

// Raw barrier: LDS ordering only (lgkmcnt(0) + s_barrier). vmcnt deliberately
// NOT drained -> prefetch global loads stay in flight across it. "memory"
// clobber pins memory ops on their side of the barrier.
__device__ __forceinline__ void bar_lds() {
    asm volatile("s_waitcnt lgkmcnt(0)" ::: "memory");
    __builtin_amdgcn_s_barrier();
    asm volatile("" ::: "memory");
}

// Gil-Werman run: emit(i, reduce(tap(i)..tap(i+9))) for i in [0,R), 1<=R<=16.
// Reads taps q in [0, R+9) only.
template<int R, bool MIN, class TapF, class EmitF>
__device__ __forceinline__ void gw_run(TapF tap, EmitF emit) {
    constexpr int C1 = (R < 8) ? R : 8;
    float4 v8, L[9];
    {
        float4 v[9];
#pragma unroll
        for (int q = 0; q < 9; q++) v[q] = tap(q);
        v8 = v[8];
        L[8] = v[8];
#pragma unroll
        for (int i = 7; i >= 0; i--) L[i] = f4op<MIN>(v[i], L[i + 1]);
    }
    float4 w[8], rr;
#pragma unroll
    for (int i = 0; i < C1; i++) {           // taps 9..8+C1
        float4 tv = tap(9 + i);
        w[i] = tv;
        rr = i ? f4op<MIN>(rr, tv) : tv;
        emit(i, f4op<MIN>(L[i], rr));
    }
    if (R > 8) {
        float4 L2[9];
        L2[8] = w[7];                        // tap 16
#pragma unroll
        for (int i = 7; i >= 1; i--) L2[i] = f4op<MIN>(w[i - 1], L2[i + 1]);
        L2[0] = f4op<MIN>(v8, L2[1]);
        float4 r2;
#pragma unroll
        for (int i = 0; i < R - 8; i++) {    // taps 17..R+8
            float4 tv = tap(17 + i);
            r2 = i ? f4op<MIN>(r2, tv) : tv;
            emit(8 + i, f4op<MIN>(L2[i], r2));
        }
    }
}

// P1 prefetch task (p in [0,5), c in [0,100)): vertical-min run over input.
// Runs {9,8,8,8,8}: s0 = 0,9,17,25,33; NT = R+9 taps. Held regs: 18 f4 max.
__device__ __forceinline__ void p1_load(const float4* __restrict__ img,
                                        int h0, int w0, bool yin,
                                        int p, int c, float4* v) {
    const int s0    = (p == 0) ? 0 : (1 + 8 * p);
    const int NT    = (p == 0) ? 18 : 17;
    const int hbase = h0 - 8 + s0;
    const int colf4 = w0 * 2 - 16 + c;
    const float4 pinf4 = make_float4(INFINITY, INFINITY, INFINITY, INFINITY);
    const bool colok = (colf4 >= 0) & (colf4 < W_F4);
    if (yin) {
        if (colok) {
            const float4* col = img + (size_t)hbase * W_F4 + colf4;
#pragma unroll
            for (int q = 0; q < 18; q++)
                if (q < NT) v[q] = col[(size_t)q * W_F4];
        } else {
#pragma unroll
            for (int q = 0; q < 18; q++) v[q] = pinf4;
        }
    } else {                                 // rim rows: per-tap mask (+inf)
#pragma unroll
        for (int q = 0; q < 18; q++)
            if (q < NT) {
                int h = hbase + q;
                bool ok = colok & (h >= 0) & (h < 512);
                v[q] = ok ? img[(size_t)h * W_F4 + colf4] : pinf4;
            }
    }
}
__device__ __forceinline__ void p1_consume(float4* __restrict__ sbuf,
                                           int p, int c, const float4* v) {
    const int s0 = (p == 0) ? 0 : (1 + 8 * p);
    if (p == 0) {
        gw_run<9, true>([&](int q) { return v[q]; },
                        [&](int i, float4 o) { sbuf[(s0 + i) * S_A + c] = o; });
    } else {
        gw_run<8, true>([&](int q) { return v[q]; },
                        [&](int i, float4 o) { sbuf[(s0 + i) * S_A + c] = o; });
    }
}

__global__ __attribute__((amdgpu_flat_work_group_size(512, 512),
                          amdgpu_waves_per_eu(2, 2)))
void opening(const float4* __restrict__ in, float4* __restrict__ out) {
    __shared__ float4 sA[2 * BUF_F4];        // 132,512 B -> 1 block/CU

    const float4 ninf4 = make_float4(-INFINITY, -INFINITY, -INFINITY, -INFINITY);

    const int t  = threadIdx.x;
    const int h0 = blockIdx.y * TH;
    const int w0 = blockIdx.x * TW;
    const int z0 = blockIdx.z * NZ;
    const bool yin = (h0 >= 8) && (h0 <= 470);            // taps h0-8..h0+41 in range
    const bool xin = (w0 >= 8) && (2 * w0 + 83 < W_F4);   // bx in [1,14]

    const int  pp = t / 100;                 // prefetch run id (4 mixed waves ok)
    const int  pc = t % 100;                 // staged f4 col
    const bool wl = t < 500;

    // ---- prologue: stage tile z0 into buf 0 (latency exposed once/block) ----
    {
        float4 v[18];
        if (wl) {
            p1_load(in + (size_t)z0 * IMG_F4, h0, w0, yin, pp, pc, v);
            p1_consume(sA, pp, pc, v);
        }
    }
    bar_lds();

    for (int k = 0; k < NZ; ++k) {
        float4* cb = sA + (size_t)(k & 1) * BUF_F4;
        float4* nb = sA + (size_t)((k + 1) & 1) * BUF_F4;

        // ---- prefetch ISSUE: next tile's taps -> regs. Loads are pinned
        //      before the first barrier below; stay in flight until consume.
        float4 v[18];
        const bool pf = wl && (k + 1 < NZ);
        if (pf) p1_load(in + (size_t)(z0 + k + 1) * IMG_F4, h0, w0, yin, pp, pc, v);

        // ---- P2: horizontal min, in place. 246 tasks: 3 runs x (c4 x 41 rows) ----
        // out px j (eroded abs w0-4+j), taps staged px j..j+9. No masks (P1
        // staged +inf for OOB cols). Max read col: 2*49+1 = 99.
        {
            const int u  = t >> 7;           // wave-uniform run id, 0..3
            const int id = t & 127;
            const bool act = (u < 3) && (id < 2 * RA);
            int base = 0, j0 = 0;
            float4 o[14];
            if (act) {
                base = (id >> 1) * S_A + (id & 1);
                j0 = u * 14;                 // 0,14,28; R = 14,14,13
                if (u < 2) gw_run<14, true>([&](int q) { return cb[base + 2 * (j0 + q)]; },
                                            [&](int i, float4 x) { o[i] = x; });
                else       gw_run<13, true>([&](int q) { return cb[base + 2 * (j0 + q)]; },
                                            [&](int i, float4 x) { o[i] = x; });
            }
            bar_lds();                       // all reads done before any write
            if (act) {
#pragma unroll
                for (int i = 0; i < 14; i++)
                    if (u < 2 || i < 13) cb[base + 2 * (j0 + i)] = o[i];
            }
        }
        bar_lds();

        // ---- P3: vertical max, rows [0,32). 164 tasks: 2 runs x 82 cols ----
        // out row o (abs h0+o), taps eroded rows o..o+9 (<= 40, exact).
        // Tap = -inf when eroded abs row h0-4+s outside [0,512).
        {
            const int u  = t >> 7;
            const int id = t & 127;
            const bool act = (u < 2) && (id < 82);
            int c3 = 0, o0 = 0;
            float4 o[16];
            if (act) {
                c3 = id;
                o0 = u * 16;
                if (yin) {
                    gw_run<16, false>([&](int q) { return cb[(o0 + q) * S_A + c3]; },
                                      [&](int i, float4 x) { o[i] = x; });
                } else {
                    gw_run<16, false>(
                        [&](int q) { int s = o0 + q; int h = h0 - 4 + s;
                                     float4 val = cb[s * S_A + c3];
                                     return ((h >= 0) & (h < 512)) ? val : ninf4; },
                        [&](int i, float4 x) { o[i] = x; });
                }
            }
            bar_lds();
            if (act) {
#pragma unroll
                for (int i = 0; i < 16; i++) cb[(o0 + i) * S_A + c3] = o[i];
            }
        }
        bar_lds();

        // ---- P4: horizontal max, px [0,32). 128 tasks: 2 runs x (c4 x 32 rows) ----
        // out px x (abs w0+x), taps eroded px x..x+9 (<= 40, exact).
        // Tap = -inf when eroded abs px w0-4+j outside [0,512).
        {
            const bool act = t < 128;
            const int u  = (t >> 6) & 1;
            const int id = t & 63;
            int base = 0, x0 = 0;
            float4 o[16];
            if (act) {
                base = (id >> 1) * S_A + (id & 1);
                x0 = u * 16;
                if (xin) {
                    gw_run<16, false>([&](int q) { return cb[base + 2 * (x0 + q)]; },
                                      [&](int i, float4 x) { o[i] = x; });
                } else {
                    gw_run<16, false>(
                        [&](int q) { int j = x0 + q; int px = w0 - 4 + j;
                                     float4 val = cb[base + 2 * j];
                                     return ((px >= 0) & (px < 512)) ? val : ninf4; },
                        [&](int i, float4 x) { o[i] = x; });
                }
            }
            bar_lds();
            if (act) {
#pragma unroll
                for (int i = 0; i < 16; i++) cb[base + 2 * (x0 + i)] = o[i];
            }
        }
        bar_lds();

        // ---- P5: coalesced store (lanes = consecutive f4, 1 KB/wave) ----
        {
            float4* oimg = out + (size_t)(z0 + k) * IMG_F4;
#pragma unroll
            for (int i = 0; i < 4; ++i) {
                int idx = t + i * 512;
                int r = idx >> 6, cc = idx & 63;
                oimg[(size_t)(h0 + r) * W_F4 + (size_t)(w0 * 2) + cc] =
                    cb[r * S_A + cc];
            }
        }

        // ---- prefetch CONSUME: first use of v[] (vmcnt wait lands here),
        //      reduce and stage into the other buffer (overlaps P5 stores) ----
        if (pf) p1_consume(nb, pp, pc, v);
        bar_lds();                           // nb staged for next iteration
    }
}

extern "C" void kernel_launch(void* const* d_in, const int* in_sizes, int n_in,
                              void* d_out, int out_size, void* d_ws, size_t ws_size,
                              hipStream_t stream) {
    const float4* in  = (const float4*)d_in[0];
    float4*       out = (float4*)d_out;
    (void)d_ws; (void)ws_size;               // workspace not needed

    dim3 grid(512 / TW, 512 / TH, 16 / NZ);  // 16 x 16 x 2 = 512 blocks
    opening<<<grid, 512, 0, stream>>>(in, out);
}

// Round 9
// 519.321 us; speedup vs baseline: 1.1636x; 1.1636x over previous
//
#include <hip/hip_runtime.h>
#include <math.h>
#include <stdint.h>

// Fused morphological opening: erode(10x10 flat, SAME) then dilate(10x10 flat,
// SAME), NHWC fp32 [16,512,512,8]. One kernel; ALL intermediates in LDS.
//
// R5/R7/R8 post-mortem: allocator pins VGPR=128 for 512-thread kernels here;
// any register-held prefetch (>=70 regs) spills catastrophically. R9 rule:
// prefetch must hold ZERO registers -> __builtin_amdgcn_global_load_lds DMA.
// Structure (per block: one (x,y) tile x NZ=8 z-images, double-buffered):
//   iter k: [issue DMA of tile k+1 raw rows -> buffer B (async, vmcnt only)]
//           [rim blocks: +inf-fill OOB cells of buffer A]
//           P1 minV (raw->minV, in place, rows 50->41)
//           P2 minH (minV->eroded, in place, cols 50->41 px)
//           P3 maxV (eroded->colmax, in place, rows 41->32)
//           P4 maxH (->opened, in place, px 41->32)
//           P5 coalesced store; s_waitcnt vmcnt(0); barrier; swap A/B.
// Phases are R4's verified full-width task maps (300/246/164/128 tasks); each
// stages reads->regs, barrier, writes (in-place safe). Global-load latency is
// OFF the critical path (DMA has ~5 phases to complete). Raw barriers
// (s_barrier + lgkmcnt(0)) never drain vmcnt mid-loop.
// Rim semantics: DMA addresses clamped to the image; OOB cells overwritten
// with +inf by fill_pads (rim blocks only) -> P1/P2 need NO masks anywhere.
// Dilation pads the *eroded* image with -inf outside [0,512): abs-row mask in
// P3 / abs-px mask in P4, rim blocks only (R4-verified scheme).
// LDS = 2 x 50 x 101 x 16 = 161,600 B (<= 160 KiB) -> 1 block/CU, 8 waves.
// Grid (16,16,2) = 512 blocks = exactly 2 sequential blocks per CU.
// Tripwire: WRITE_SIZE must be exactly 131072 KB (no spill).

#define W_F4   1024              // 512 px * 2 f4 (8 ch)
#define IMG_F4 (512 * W_F4)
#define TH     32                // output rows per tile (512/32 = 16 bands)
#define TW     32                // output px per tile
#define RR     50                // raw rows staged = TH + 18
#define RE     41                // minV/eroded rows = TH + 9
#define CA     100               // staged cols (f4) = (TW + 18) * 2
#define S_A    101               // row stride (f4)
#define BUF_F4 (RR * S_A)        // 5050 f4 = 80,800 B per buffer
#define NZ     8                 // z-images per block

__device__ __forceinline__ float4 f4min(float4 a, float4 b) {
    return make_float4(fminf(a.x,b.x), fminf(a.y,b.y), fminf(a.z,b.z), fminf(a.w,b.w));
}
__device__ __forceinline__ float4 f4max(float4 a, float4 b) {
    return make_float4(fmaxf(a.x,b.x), fmaxf(a.y,b.y), fmaxf(a.z,b.z), fmaxf(a.w,b.w));
}
template<bool MIN>
__device__ __forceinline__ float4 f4op(float4 a, float4 b) {
    return MIN ? f4min(a, b) : f4max(a, b);
}

// Raw barrier: LDS ordering only (lgkmcnt(0) + s_barrier). vmcnt deliberately
// NOT drained -> DMA prefetch stays in flight across it.
__device__ __forceinline__ void bar_lds() {
    asm volatile("s_waitcnt lgkmcnt(0)" ::: "memory");
    __builtin_amdgcn_s_barrier();
    asm volatile("" ::: "memory");
}

// 16-byte global->LDS DMA (zero VGPR staging). gaddr per-lane; LDS dest =
// wave-uniform base + lane*16.
__device__ __forceinline__ void dma16(const float4* g, float4* l) {
    typedef __attribute__((address_space(1))) const void gvoid;
    typedef __attribute__((address_space(3))) void svoid;
    __builtin_amdgcn_global_load_lds((gvoid*)(uintptr_t)g,
                                     (svoid*)(uintptr_t)l, 16, 0, 0);
}

// Gil-Werman run: emit(i, reduce(tap(i)..tap(i+9))) for i in [0,R), 1<=R<=16.
template<int R, bool MIN, class TapF, class EmitF>
__device__ __forceinline__ void gw_run(TapF tap, EmitF emit) {
    constexpr int C1 = (R < 8) ? R : 8;
    float4 v8, L[9];
    {
        float4 v[9];
#pragma unroll
        for (int q = 0; q < 9; q++) v[q] = tap(q);
        v8 = v[8];
        L[8] = v[8];
#pragma unroll
        for (int i = 7; i >= 0; i--) L[i] = f4op<MIN>(v[i], L[i + 1]);
    }
    float4 w[8], rr;
#pragma unroll
    for (int i = 0; i < C1; i++) {           // taps 9..8+C1
        float4 tv = tap(9 + i);
        w[i] = tv;
        rr = i ? f4op<MIN>(rr, tv) : tv;
        emit(i, f4op<MIN>(L[i], rr));
    }
    if (R > 8) {
        float4 L2[9];
        L2[8] = w[7];                        // tap 16
#pragma unroll
        for (int i = 7; i >= 1; i--) L2[i] = f4op<MIN>(w[i - 1], L2[i + 1]);
        L2[0] = f4op<MIN>(v8, L2[1]);
        float4 r2;
#pragma unroll
        for (int i = 0; i < R - 8; i++) {    // taps 17..R+8
            float4 tv = tap(17 + i);
            r2 = i ? f4op<MIN>(r2, tv) : tv;
            emit(8 + i, f4op<MIN>(L2[i], r2));
        }
    }
}

// Issue the 100 (row, half) DMA tasks for one raw tile. Wave-uniform task ->
// all 64 lanes cooperate; per-lane global col clamped (rim garbage is
// overwritten by fill_pads before use).
__device__ __forceinline__ void stage_issue(const float4* __restrict__ img,
                                            float4* __restrict__ nb,
                                            int h0, int w0, int wave, int lane) {
    for (int i = wave; i < 2 * RR; i += 8) { // 12-13 DMA instrs per wave
        const int s = i >> 1;
        const int h = h0 - 8 + s;
        if ((h < 0) | (h >= 512)) continue;  // wave-uniform skip; filled +inf
        const int c0 = (i & 1) ? 36 : 0;     // halves cover cols 0..63, 36..99
        int colf4 = w0 * 2 - 16 + c0 + lane;
        colf4 = min(max(colf4, 0), W_F4 - 1);
        dma16(img + (size_t)h * W_F4 + colf4, nb + s * S_A + c0);
    }
}

// Overwrite OOB cells with +inf (erosion SAME pad). Rim blocks only.
__device__ __forceinline__ void fill_pads(float4* __restrict__ cb,
                                          int h0, int w0, int t) {
    const float4 pinf4 = make_float4(INFINITY, INFINITY, INFINITY, INFINITY);
    for (int idx = t; idx < RR * CA; idx += 512) {
        const int s = idx / CA;
        const int c = idx - s * CA;
        const int h = h0 - 8 + s;
        const int colf4 = w0 * 2 - 16 + c;
        if ((h < 0) | (h >= 512) | (colf4 < 0) | (colf4 >= W_F4))
            cb[s * S_A + c] = pinf4;
    }
}

__global__ __launch_bounds__(512, 2)
void opening(const float4* __restrict__ in, float4* __restrict__ out) {
    __shared__ float4 sA[2 * BUF_F4];        // 161,600 B -> 1 block/CU

    const float4 ninf4 = make_float4(-INFINITY, -INFINITY, -INFINITY, -INFINITY);

    const int t    = threadIdx.x;
    const int wave = t >> 6, lane = t & 63;
    const int h0 = blockIdx.y * TH;
    const int w0 = blockIdx.x * TW;
    const int z0 = blockIdx.z * NZ;
    const bool yin = (h0 >= 8) && (h0 + 41 < 512);        // raw rows all valid
    const bool xin = (w0 >= 8) && (w0 * 2 + 83 < W_F4);   // staged cols valid
    const bool rim = !(yin && xin);

    // ---- prologue: DMA tile z0 -> buf 0 (latency exposed once per block) ----
    stage_issue(in + (size_t)z0 * IMG_F4, sA, h0, w0, wave, lane);
    asm volatile("s_waitcnt vmcnt(0)" ::: "memory");
    bar_lds();

    for (int k = 0; k < NZ; ++k) {
        float4* cb = sA + (size_t)(k & 1) * BUF_F4;
        float4* nb = sA + (size_t)((k + 1) & 1) * BUF_F4;

        // ---- async: issue next tile's DMA (completion checked at iter end) ----
        if (k + 1 < NZ)
            stage_issue(in + (size_t)(z0 + k + 1) * IMG_F4, nb, h0, w0, wave, lane);

        // ---- rim: +inf pads on current buffer (DMA'd last iter, barriered) ----
        if (rim) {
            fill_pads(cb, h0, w0, t);
            bar_lds();
        }

        // ---- P1: vertical min, raw->minV in place. 300 tasks: 100 cols x
        //      runs {16,16,9} (s0 = 0,16,32). Taps raw rows s0+q <= 49.
        //      No masks: pads pre-staged +inf. ----
        {
            const int u  = t >> 7;
            const int id = t & 127;
            const bool act = (u < 3) && (id < CA);
            const int s0 = u * 16;
            float4 o[16];
            if (act) {
                if (u < 2) gw_run<16, true>([&](int q) { return cb[(s0 + q) * S_A + id]; },
                                            [&](int i, float4 x) { o[i] = x; });
                else       gw_run<9,  true>([&](int q) { return cb[(s0 + q) * S_A + id]; },
                                            [&](int i, float4 x) { o[i] = x; });
            }
            bar_lds();                       // all raw reads done before writes
            if (act) {
                const int Rn = (u < 2) ? 16 : 9;
#pragma unroll
                for (int i = 0; i < 16; i++)
                    if (i < Rn) cb[(s0 + i) * S_A + id] = o[i];
            }
        }
        bar_lds();

        // ---- P2: horizontal min, minV->eroded in place. 246 tasks:
        //      (c4 x 41 rows) x runs {14,14,13}. Taps px j0+q (col <= 99). ----
        {
            const int u  = t >> 7;
            const int id = t & 127;
            const bool act = (u < 3) && (id < 2 * RE);
            int base = 0, j0 = 0;
            float4 o[14];
            if (act) {
                base = (id >> 1) * S_A + (id & 1);
                j0 = u * 14;                 // 0,14,28; R = 14,14,13
                if (u < 2) gw_run<14, true>([&](int q) { return cb[base + 2 * (j0 + q)]; },
                                            [&](int i, float4 x) { o[i] = x; });
                else       gw_run<13, true>([&](int q) { return cb[base + 2 * (j0 + q)]; },
                                            [&](int i, float4 x) { o[i] = x; });
            }
            bar_lds();
            if (act) {
                const int Rn = (u < 2) ? 14 : 13;
#pragma unroll
                for (int i = 0; i < 14; i++)
                    if (i < Rn) cb[base + 2 * (j0 + i)] = o[i];
            }
        }
        bar_lds();

        // ---- P3: vertical max, rows 41->32 in place. 164 tasks: 82 cols x
        //      runs {16,16}. Tap = -inf when eroded abs row OOB (rim only). ----
        {
            const int u  = t >> 7;
            const int id = t & 127;
            const bool act = (u < 2) && (id < 82);
            const int o0 = u * 16;
            float4 o[16];
            if (act) {
                if (yin) {
                    gw_run<16, false>([&](int q) { return cb[(o0 + q) * S_A + id]; },
                                      [&](int i, float4 x) { o[i] = x; });
                } else {
                    gw_run<16, false>(
                        [&](int q) { int s = o0 + q; int h = h0 - 4 + s;
                                     float4 val = cb[s * S_A + id];
                                     return ((h >= 0) & (h < 512)) ? val : ninf4; },
                        [&](int i, float4 x) { o[i] = x; });
                }
            }
            bar_lds();
            if (act) {
#pragma unroll
                for (int i = 0; i < 16; i++) cb[(o0 + i) * S_A + id] = o[i];
            }
        }
        bar_lds();

        // ---- P4: horizontal max, px 41->32 in place. 128 tasks: (c4 x 32
        //      rows) x runs {16,16}. Tap = -inf when eroded abs px OOB. ----
        {
            const bool act = t < 128;
            const int u  = (t >> 6) & 1;
            const int id = t & 63;
            int base = 0, x0 = 0;
            float4 o[16];
            if (act) {
                base = (id >> 1) * S_A + (id & 1);
                x0 = u * 16;
                if (xin) {
                    gw_run<16, false>([&](int q) { return cb[base + 2 * (x0 + q)]; },
                                      [&](int i, float4 x) { o[i] = x; });
                } else {
                    gw_run<16, false>(
                        [&](int q) { int j = x0 + q; int px = w0 - 4 + j;
                                     float4 val = cb[base + 2 * j];
                                     return ((px >= 0) & (px < 512)) ? val : ninf4; },
                        [&](int i, float4 x) { o[i] = x; });
                }
            }
            bar_lds();
            if (act) {
#pragma unroll
                for (int i = 0; i < 16; i++) cb[base + 2 * (x0 + i)] = o[i];
            }
        }
        bar_lds();

        // ---- P5: coalesced store (lanes = consecutive f4, 1 KB/wave) ----
        {
            float4* oimg = out + (size_t)(z0 + k) * IMG_F4;
#pragma unroll
            for (int i = 0; i < 4; ++i) {
                const int idx = t + i * 512;
                const int r = idx >> 6, cc = idx & 63;
                oimg[(size_t)(h0 + r) * W_F4 + (size_t)(w0 * 2) + cc] =
                    cb[r * S_A + cc];
            }
        }

        // ---- drain: next tile's DMA complete; all P5 reads of cb done ----
        asm volatile("s_waitcnt vmcnt(0)" ::: "memory");
        bar_lds();
    }
}

extern "C" void kernel_launch(void* const* d_in, const int* in_sizes, int n_in,
                              void* d_out, int out_size, void* d_ws, size_t ws_size,
                              hipStream_t stream) {
    const float4* in  = (const float4*)d_in[0];
    float4*       out = (float4*)d_out;
    (void)d_ws; (void)ws_size;               // workspace not needed

    dim3 grid(512 / TW, 512 / TH, 16 / NZ);  // 16 x 16 x 2 = 512 blocks
    opening<<<grid, 512, 0, stream>>>(in, out);
}